// Round 12
// baseline (1034.630 us; speedup 1.0000x reference)
//
#include <hip/hip_runtime.h>
#include <hip/hip_bf16.h>
#include <cstdint>
#include <cmath>

#define T_TOK 4096
#define DIM   768
#define HEADS 12
#define HD    64
#define NEXP  8
#define FDIM  3072

typedef __attribute__((ext_vector_type(8))) short short8v;
typedef __attribute__((ext_vector_type(4))) float float4v;

__device__ __forceinline__ float gelu_tanh(float x) {
  // matches jax.nn.gelu(approximate=True)
  float u = 0.7978845608028654f * (x + 0.044715f * x * x * x);
  return 0.5f * x * (1.0f + tanhf(u));
}

__device__ __forceinline__ short f2bf(float x) {
  __hip_bfloat16 h = __float2bfloat16(x);
  return *reinterpret_cast<short*>(&h);
}

// async global->LDS 16B copy: dest = (wave-uniform lds base) + lane*16,
// src is per-lane. LDS generic ptr low 32 bits == LDS byte offset on gfx9+.
__device__ __forceinline__ void gld16(void* lds, const void* g) {
  __builtin_amdgcn_global_load_lds(
      (__attribute__((address_space(1))) void*)(uintptr_t)g,
      (__attribute__((address_space(3))) void*)(uint32_t)(uintptr_t)lds,
      16, 0, 0);
}

#define FMA4(a, p, v) \
  (a).x = fmaf(p, (v).x, (a).x); (a).y = fmaf(p, (v).y, (a).y); \
  (a).z = fmaf(p, (v).z, (a).z); (a).w = fmaf(p, (v).w, (a).w)
#define ADD4(a, v) \
  (a).x += (v).x; (a).y += (v).y; (a).z += (v).z; (a).w += (v).w

// ---------------- fp32 tiled GEMM (attention path only: QKV, o-proj) --------
// float4-vectorized staging, 16x16 thread grid, BK=16.
// BFOUT: additionally write bf16 copy of C (fused y2bf for the o-proj).
template<int TBM, int TBN, bool BFOUT>
__global__ __launch_bounds__(256) void gemm_f32(
    const float* __restrict__ A, const float* __restrict__ W,
    const float* __restrict__ bias, float* __restrict__ C,
    short* __restrict__ Cbf, int M, int N, int K)
{
  constexpr int MM = TBM / 16;
  constexpr int MN = TBN / 16;
  constexpr int AL4 = TBM / 64;   // float4 A loads per thread
  constexpr int BL4 = TBN / 64;
  __shared__ float As[16][TBM + 4];
  __shared__ float Bs[16][TBN + 4];
  const int bm = blockIdx.y * TBM;
  const int bn = blockIdx.x * TBN;
  const int tid = threadIdx.x;
  const int tr = tid >> 4;
  const int tc = tid & 15;

  float acc[MM][MN] = {};

  for (int k0 = 0; k0 < K; k0 += 16) {
    #pragma unroll
    for (int i = 0; i < AL4; i++) {
      int fidx = tid + i * 256;
      int row = fidx >> 2, c4 = fidx & 3;
      float4 v = *(const float4*)&A[(size_t)(bm + row) * K + k0 + c4 * 4];
      As[c4 * 4 + 0][row] = v.x;
      As[c4 * 4 + 1][row] = v.y;
      As[c4 * 4 + 2][row] = v.z;
      As[c4 * 4 + 3][row] = v.w;
    }
    #pragma unroll
    for (int i = 0; i < BL4; i++) {
      int fidx = tid + i * 256;
      int kk = fidx / (TBN / 4), n4 = fidx % (TBN / 4);
      *(float4*)&Bs[kk][n4 * 4] =
          *(const float4*)&W[(size_t)(k0 + kk) * N + bn + n4 * 4];
    }
    __syncthreads();
    #pragma unroll
    for (int kk = 0; kk < 16; kk++) {
      float a[MM], b[MN];
      #pragma unroll
      for (int u4 = 0; u4 < MM / 4; u4++) {
        float4 t = *(const float4*)&As[kk][tr * MM + u4 * 4];
        a[u4*4+0]=t.x; a[u4*4+1]=t.y; a[u4*4+2]=t.z; a[u4*4+3]=t.w;
      }
      #pragma unroll
      for (int v4 = 0; v4 < MN / 4; v4++) {
        float4 t = *(const float4*)&Bs[kk][tc * MN + v4 * 4];
        b[v4*4+0]=t.x; b[v4*4+1]=t.y; b[v4*4+2]=t.z; b[v4*4+3]=t.w;
      }
      #pragma unroll
      for (int u = 0; u < MM; u++)
        #pragma unroll
        for (int v = 0; v < MN; v++)
          acc[u][v] = fmaf(a[u], b[v], acc[u][v]);
    }
    __syncthreads();
  }

  #pragma unroll
  for (int u = 0; u < MM; u++) {
    int row = bm + tr * MM + u;
    #pragma unroll
    for (int v4 = 0; v4 < MN / 4; v4++) {
      int col = bn + tc * MN + v4 * 4;
      float4 o;
      o.x = acc[u][v4*4+0] + bias[col+0];
      o.y = acc[u][v4*4+1] + bias[col+1];
      o.z = acc[u][v4*4+2] + bias[col+2];
      o.w = acc[u][v4*4+3] + bias[col+3];
      *(float4*)&C[(size_t)row * N + col] = o;
      if (BFOUT) {
        short4 s = make_short4(f2bf(o.x), f2bf(o.y), f2bf(o.z), f2bf(o.w));
        *(short4*)&Cbf[(size_t)row * N + col] = s;
      }
    }
  }
}

// ---------------- transpose + fp32->bf16 convert: W[K][N] -> WT[N][K] -------
__global__ __launch_bounds__(256) void transpose_bf16(
    const float* __restrict__ W, short* __restrict__ WT, int K, int N)
{
  __shared__ float t[32][33];
  const size_t mat = (size_t)K * N;
  const float* Wp = W + blockIdx.z * mat;
  short* WTp = WT + blockIdx.z * mat;
  int n0 = blockIdx.x * 32, k0 = blockIdx.y * 32;
  int tx = threadIdx.x, ty = threadIdx.y;  // 32 x 8
  #pragma unroll
  for (int i = 0; i < 4; i++)
    t[ty + i * 8][tx] = Wp[(size_t)(k0 + ty + i * 8) * N + n0 + tx];
  __syncthreads();
  #pragma unroll
  for (int i = 0; i < 4; i++)
    WTp[(size_t)(n0 + ty + i * 8) * K + k0 + tx] = f2bf(t[tx][ty + i * 8]);
}

// ---------------- unified MoE GEMM: 128x128 tile, BK=32, gld16 staging -----
// MODE 1 (up):   hbuf[start+r] = gelu(bf16(gather(ybf)@WT^T + b1))
// MODE 2 (down): oe[start+r]   = hbuf[start+r]@WT^T + b2   (fp32)
// Grid: (row-tile FASTEST for B-panel L2 reuse, N-panel on y).
template<int MODE>
__global__ __launch_bounds__(256) void moe_mm(
    const short* __restrict__ A, const short* __restrict__ WT,
    const float* __restrict__ bias, void* __restrict__ Cout,
    int N, int K,
    const int* __restrict__ offsets, const int* __restrict__ perm,
    const int* __restrict__ tmap, const int* __restrict__ tilecnt)
{
  const int bx = blockIdx.x;
  if (bx >= tilecnt[0]) return;
  const int info  = tmap[bx];
  const int e     = info >> 16;
  const int start = offsets[e];
  const int M     = offsets[e + 1] - start;
  const int bm    = (info & 0xffff) * 128;
  const int bn    = blockIdx.y * 128;

  __shared__ short As[4][128][8];   // [kslot][row][16B]
  __shared__ short Bs[4][128][8];
  __shared__ int   perm_s[128];

  const int tid  = threadIdx.x;
  const int lane = tid & 63;
  const int wave = tid >> 6;        // staging kslot AND (wm,wn) quadrant
  const int wm = wave >> 1, wn = wave & 1;
  const int lr = lane & 15;
  const int kb = lane >> 4;

  const short* WTe = WT + (size_t)e * ((size_t)N * K);
  const float* be  = bias + (size_t)e * N;

  if (MODE == 1) {
    if (tid < 128) {
      int rr = bm + tid;
      perm_s[tid] = (rr < M) ? perm[start + rr] : perm[start];
    }
    __syncthreads();
  }

  const short* asrc0;
  const short* asrc1;
  if (MODE == 1) {
    asrc0 = A + (size_t)perm_s[lane] * K + wave * 8;
    asrc1 = A + (size_t)perm_s[64 + lane] * K + wave * 8;
  } else {
    int r0 = bm + lane;      if (r0 >= M) r0 = M - 1;
    int r1 = bm + 64 + lane; if (r1 >= M) r1 = M - 1;
    asrc0 = A + (size_t)(start + r0) * K + wave * 8;
    asrc1 = A + (size_t)(start + r1) * K + wave * 8;
  }
  const short* bsrc0 = WTe + (size_t)(bn + lane) * K + wave * 8;
  const short* bsrc1 = WTe + (size_t)(bn + 64 + lane) * K + wave * 8;
  short* adst0 = &As[wave][0][0];
  short* adst1 = &As[wave][64][0];
  short* bdst0 = &Bs[wave][0][0];
  short* bdst1 = &Bs[wave][64][0];

  float4v acc[4][4] = {};

  for (int k0 = 0; k0 < K; k0 += 32) {
    __syncthreads();                 // previous iteration's LDS reads done
    gld16(adst0, asrc0 + k0);
    gld16(adst1, asrc1 + k0);
    gld16(bdst0, bsrc0 + k0);
    gld16(bdst1, bsrc1 + k0);
    __syncthreads();                 // drains vmcnt -> tiles visible

    short8v af[4], bfv[4];
    #pragma unroll
    for (int mi = 0; mi < 4; mi++)
      af[mi] = *(const short8v*)&As[kb][wm * 64 + mi * 16 + lr][0];
    #pragma unroll
    for (int ni = 0; ni < 4; ni++)
      bfv[ni] = *(const short8v*)&Bs[kb][wn * 64 + ni * 16 + lr][0];
    #pragma unroll
    for (int mi = 0; mi < 4; mi++)
      #pragma unroll
      for (int ni = 0; ni < 4; ni++)
        acc[mi][ni] = __builtin_amdgcn_mfma_f32_16x16x32_bf16(
            af[mi], bfv[ni], acc[mi][ni], 0, 0, 0);
  }

  // D mapping: col = lane&15, row = (lane>>4)*4 + reg
  #pragma unroll
  for (int ni = 0; ni < 4; ni++) {
    int col = bn + wn * 64 + ni * 16 + lr;
    float b = be[col];
    #pragma unroll
    for (int mi = 0; mi < 4; mi++) {
      int lrow0 = wm * 64 + mi * 16 + kb * 4;
      #pragma unroll
      for (int r = 0; r < 4; r++) {
        int rr = bm + lrow0 + r;
        if (rr < M) {
          if (MODE == 1) {
            short* C = (short*)Cout;
            C[(size_t)(start + rr) * N + col] = f2bf(gelu_tanh(acc[mi][ni][r] + b));
          } else {
            float* C = (float*)Cout;
            C[(size_t)(start + rr) * N + col] = acc[mi][ni][r] + b;
          }
        }
      }
    }
  }
}

// ---------------- combine: out[t] = g0*oe[p0] + g1*oe[p1] -------------------
__global__ __launch_bounds__(256) void combine_kernel(
    const float* __restrict__ oe, const int* __restrict__ ppos,
    const float* __restrict__ topg, float* __restrict__ out)
{
  int g = blockIdx.x * 256 + threadIdx.x;
  int t = g / 192;
  int c = (g - t * 192) * 4;
  int p0 = ppos[2 * t], p1 = ppos[2 * t + 1];
  float g0 = topg[2 * t], g1 = topg[2 * t + 1];
  float4 a = *(const float4*)&oe[(size_t)p0 * DIM + c];
  float4 b = *(const float4*)&oe[(size_t)p1 * DIM + c];
  float4 o;
  o.x = g0 * a.x + g1 * b.x;
  o.y = g0 * a.y + g1 * b.y;
  o.z = g0 * a.z + g1 * b.z;
  o.w = g0 * a.w + g1 * b.w;
  *(float4*)&out[(size_t)t * DIM + c] = o;
}

// ---------------- attention (fp32, no-max softmax, lane-owns-query) --------
// grid (16, 48), block 256 = 4 waves (kq = key-quarter 0..3).
// Each lane owns ONE query: q[64 dims] and acc[64 dims] in registers.
// K/V tiles staged via gld16; k/v LDS reads are wave-uniform broadcasts.
// NO shuffles. 4-stage pairwise combine (r8 scheme) via ks/vs scratch.
__global__ __launch_bounds__(256) void attn_kernel(
    const float* __restrict__ qkv, float* __restrict__ ctx)
{
  const int qt = blockIdx.x;
  const int bh = blockIdx.y;
  const int b = bh / HEADS, h = bh % HEADS;
  const float* base = qkv + (size_t)b * 1024 * (3 * DIM) + h * 64;

  __shared__ float ks[64 * 64];   // K tile; combine scratch
  __shared__ float vs[64 * 64];   // V tile; combine scratch
  __shared__ float lred[2][64];

  const int tid  = threadIdx.x;
  const int kq   = tid >> 6;      // 0..3: key quarter
  const int lane = tid & 63;      // query index within the 64-query tile

  const float qscale = 0.125f * 1.44269504088896f;  // fold 1/sqrt(64), log2e

  float4 q[16], acc[16];
  #pragma unroll
  for (int i = 0; i < 16; i++) acc[i] = make_float4(0.f, 0.f, 0.f, 0.f);
  float l = 0.f;

  {
    const float* qp = base + (size_t)(qt * 64 + lane) * (3 * DIM);
    #pragma unroll
    for (int i = 0; i < 16; i++) {
      float4 t = *(const float4*)(qp + i * 4);
      q[i] = make_float4(t.x * qscale, t.y * qscale, t.z * qscale, t.w * qscale);
    }
  }

  const float4* ks4 = (const float4*)ks;
  const float4* vs4 = (const float4*)vs;

  for (int kt = 0; kt < 16; kt++) {
    __syncthreads();                    // previous tile's reads complete
    #pragma unroll
    for (int i = 0; i < 4; i++) {
      int idx = tid + i * 256;          // 0..1023
      int r = idx >> 4, c4 = idx & 15;
      const float* kp = base + (size_t)(kt * 64 + r) * (3 * DIM) + c4 * 4;
      gld16(&ks[idx * 4], kp + DIM);
      gld16(&vs[idx * 4], kp + 2 * DIM);
    }
    __syncthreads();                    // drains vmcnt -> tiles visible

    #pragma unroll 2
    for (int jj = 0; jj < 16; jj++) {
      int j = kq * 16 + jj;
      float s0 = 0.f, s1 = 0.f, s2 = 0.f, s3 = 0.f;
      #pragma unroll
      for (int c = 0; c < 4; c++) {
        float4 k0 = ks4[j * 16 + c * 4 + 0];
        float4 k1 = ks4[j * 16 + c * 4 + 1];
        float4 k2 = ks4[j * 16 + c * 4 + 2];
        float4 k3 = ks4[j * 16 + c * 4 + 3];
        s0 = fmaf(q[c*4+0].x, k0.x, s0); s0 = fmaf(q[c*4+0].y, k0.y, s0);
        s0 = fmaf(q[c*4+0].z, k0.z, s0); s0 = fmaf(q[c*4+0].w, k0.w, s0);
        s1 = fmaf(q[c*4+1].x, k1.x, s1); s1 = fmaf(q[c*4+1].y, k1.y, s1);
        s1 = fmaf(q[c*4+1].z, k1.z, s1); s1 = fmaf(q[c*4+1].w, k1.w, s1);
        s2 = fmaf(q[c*4+2].x, k2.x, s2); s2 = fmaf(q[c*4+2].y, k2.y, s2);
        s2 = fmaf(q[c*4+2].z, k2.z, s2); s2 = fmaf(q[c*4+2].w, k2.w, s2);
        s3 = fmaf(q[c*4+3].x, k3.x, s3); s3 = fmaf(q[c*4+3].y, k3.y, s3);
        s3 = fmaf(q[c*4+3].z, k3.z, s3); s3 = fmaf(q[c*4+3].w, k3.w, s3);
      }
      float p = exp2f((s0 + s1) + (s2 + s3));
      l += p;
      #pragma unroll
      for (int c = 0; c < 4; c++) {
        float4 v0 = vs4[j * 16 + c * 4 + 0];
        float4 v1 = vs4[j * 16 + c * 4 + 1];
        float4 v2 = vs4[j * 16 + c * 4 + 2];
        float4 v3 = vs4[j * 16 + c * 4 + 3];
        FMA4(acc[c*4+0], p, v0);
        FMA4(acc[c*4+1], p, v1);
        FMA4(acc[c*4+2], p, v2);
        FMA4(acc[c*4+3], p, v3);
      }
    }
  }

  // 4-stage pairwise combine across kq waves using ks/vs as scratch.
  // Lane region: 64 floats at [lane*64 .. lane*64+63].
  float* myks = ks + lane * 64;
  float* myvs = vs + lane * 64;

  __syncthreads();
  if (kq == 2 || kq == 3) {
    float* buf = (kq == 2) ? myks : myvs;
    #pragma unroll
    for (int i = 0; i < 16; i++) *(float4*)&buf[i * 4] = acc[i];
    lred[kq - 2][lane] = l;
  }
  __syncthreads();
  if (kq == 0 || kq == 1) {
    const float* buf = (kq == 0) ? myks : myvs;
    #pragma unroll
    for (int i = 0; i < 16; i++) {
      float4 t = *(const float4*)&buf[i * 4];
      ADD4(acc[i], t);
    }
    l += lred[kq][lane];
  }
  __syncthreads();
  if (kq == 1) {
    #pragma unroll
    for (int i = 0; i < 16; i++) *(float4*)&myks[i * 4] = acc[i];
    lred[0][lane] = l;
  }
  __syncthreads();
  if (kq == 0) {
    #pragma unroll
    for (int i = 0; i < 16; i++) {
      float4 t = *(const float4*)&myks[i * 4];
      ADD4(acc[i], t);
    }
    l += lred[0][lane];
    float inv = 1.f / l;
    float* op = ctx + ((size_t)b * 1024 + qt * 64 + lane) * DIM + h * 64;
    #pragma unroll
    for (int i = 0; i < 16; i++) {
      float4 o = make_float4(acc[i].x * inv, acc[i].y * inv,
                             acc[i].z * inv, acc[i].w * inv);
      *(float4*)(op + i * 4) = o;
    }
  }
}

// ---------------- router ----------------
__global__ __launch_bounds__(256) void router_kernel(
    const float* __restrict__ y, const float* __restrict__ wr,
    float* __restrict__ probs, int* __restrict__ topi,
    float* __restrict__ topg, int* __restrict__ counts)
{
  __shared__ float w[DIM * NEXP];
  const int tid = threadIdx.x;
  for (int i = tid; i < DIM * NEXP; i += 256) w[i] = wr[i];
  __syncthreads();

  const int t = blockIdx.x * 256 + tid;
  const float* yp = y + (size_t)t * DIM;
  float logit[8] = {};
  for (int d = 0; d < DIM; d++) {
    float xv = yp[d];
    #pragma unroll
    for (int e = 0; e < 8; e++) logit[e] = fmaf(xv, w[d * 8 + e], logit[e]);
  }
  float mx = logit[0];
  #pragma unroll
  for (int e = 1; e < 8; e++) mx = fmaxf(mx, logit[e]);
  float p[8], sum = 0.f;
  #pragma unroll
  for (int e = 0; e < 8; e++) { p[e] = __expf(logit[e] - mx); sum += p[e]; }
  float inv = 1.f / sum;
  #pragma unroll
  for (int e = 0; e < 8; e++) { p[e] *= inv; probs[(size_t)t * 8 + e] = p[e]; }

  int i0 = 0;
  #pragma unroll
  for (int e = 1; e < 8; e++) if (p[e] > p[i0]) i0 = e;
  int i1 = (i0 == 0) ? 1 : 0;
  #pragma unroll
  for (int e = 0; e < 8; e++) if (e != i0 && p[e] > p[i1]) i1 = e;
  float g = p[i0] + p[i1];
  topi[2 * t] = i0;  topi[2 * t + 1] = i1;
  topg[2 * t] = p[i0] / g;  topg[2 * t + 1] = p[i1] / g;
  atomicAdd(&counts[i0], 1);
  atomicAdd(&counts[i1], 1);
}

__global__ void init_meta(int* counts) {
  if (threadIdx.x < 8) counts[threadIdx.x] = 0;
}

// scan + compact 128-row tile map (shared by up and down)
__global__ void scan_kernel(const int* __restrict__ counts,
                            int* __restrict__ offsets, int* __restrict__ cursors,
                            int* __restrict__ tmap, int* __restrict__ tilecnt) {
  if (threadIdx.x == 0) {
    int s = 0;
    for (int e = 0; e < 8; e++) { offsets[e] = s; cursors[e] = s; s += counts[e]; }
    offsets[8] = s;
    int tu = 0;
    for (int e = 0; e < 8; e++) {
      int m = counts[e];
      for (int t = 0; t * 128 < m; t++) tmap[tu++] = (e << 16) | t;
    }
    tilecnt[0] = tu;
  }
}

__global__ __launch_bounds__(256) void scatter_kernel(
    const int* __restrict__ topi, int* __restrict__ cursors,
    int* __restrict__ perm, int* __restrict__ ppos)
{
  const int t = blockIdx.x * 256 + threadIdx.x;
  #pragma unroll
  for (int s = 0; s < 2; s++) {
    int e = topi[2 * t + s];
    int pos = atomicAdd(&cursors[e], 1);
    perm[pos] = t;
    ppos[2 * t + s] = pos;
  }
}

// ---------------- launch ----------------
extern "C" void kernel_launch(void* const* d_in, const int* in_sizes, int n_in,
                              void* d_out, int out_size, void* d_ws, size_t ws_size,
                              hipStream_t stream) {
  const float* x        = (const float*)d_in[0];
  const float* w_qkv    = (const float*)d_in[1];
  const float* b_qkv    = (const float*)d_in[2];
  const float* w_o      = (const float*)d_in[3];
  const float* b_o      = (const float*)d_in[4];
  const float* w_router = (const float*)d_in[5];
  const float* w1       = (const float*)d_in[6];
  const float* b1       = (const float*)d_in[7];
  const float* w2       = (const float*)d_in[8];
  const float* b2       = (const float*)d_in[9];

  float* out   = (float*)d_out;
  float* probs = out + (size_t)T_TOK * DIM;

  char* ws = (char*)d_ws;
  // region A [0, 50331648): qkv f32 (37.75MB) -> hbuf bf16 (50.33MB)
  float* qkv  = (float*)ws;
  short* hbuf = (short*)ws;
  // wT [50331648, 88080384)
  short* wT   = (short*)(ws + 50331648);
  // region C [88080384, 113246208): ctx f32 | later oe f32
  float* ctx  = (float*)(ws + 88080384);
  float* oe   = (float*)(ws + 88080384);
  float* y    = (float*)(ws + 100663296);    // 12.58MB: y f32 [4096*768]
  short* ybf  = (short*)(ws + 113246208);    // 6.29MB: y bf16
  char*  meta = ws + 119537664;
  int*   counts  = (int*)meta;
  int*   cursors = counts + 8;
  int*   offsets = cursors + 8;              // 16 slots
  int*   topi    = offsets + 16;             // 8192
  float* topg    = (float*)(topi + 8192);
  int*   perm    = (int*)(topg + 8192);
  int*   ppos    = perm + 8192;
  int*   tmap    = ppos + 8192;              // <= 72
  int*   tilecnt = tmap + 80;

  init_meta<<<1, 64, 0, stream>>>(counts);

  // QKV (fp32): [4096,768] @ [768,2304]
  gemm_f32<128, 64, false><<<dim3((3 * DIM) / 64, T_TOK / 128), 256, 0, stream>>>(
      x, w_qkv, b_qkv, qkv, nullptr, T_TOK, 3 * DIM, DIM);

  attn_kernel<<<dim3(16, 48), 256, 0, stream>>>(qkv, ctx);

  // output proj (fp32): [4096,768] @ [768,768]; fused bf16 copy for MoE
  gemm_f32<64, 64, true><<<dim3(DIM / 64, T_TOK / 64), 256, 0, stream>>>(
      ctx, w_o, b_o, y, ybf, T_TOK, DIM, DIM);

  router_kernel<<<16, 256, 0, stream>>>(y, w_router, probs, topi, topg, counts);
  scan_kernel<<<1, 64, 0, stream>>>(counts, offsets, cursors, tmap, tilecnt);
  scatter_kernel<<<16, 256, 0, stream>>>(topi, cursors, perm, ppos);

  // w1 [8][768][3072] -> w1t bf16 [8][3072][768]
  transpose_bf16<<<dim3(FDIM / 32, DIM / 32, NEXP), dim3(32, 8), 0, stream>>>(
      w1, wT, DIM, FDIM);
  // up: row-tiles fastest (L2 B-panel reuse), <=72 active tiles
  moe_mm<1><<<dim3(72, FDIM / 128), 256, 0, stream>>>(
      ybf, wT, b1, hbuf, FDIM, DIM, offsets, perm, tmap, tilecnt);

  // w2 [8][3072][768] -> w2t bf16 [8][768][3072]
  transpose_bf16<<<dim3(DIM / 32, FDIM / 32, NEXP), dim3(32, 8), 0, stream>>>(
      w2, wT, FDIM, DIM);
  // down: same 128-row tile map
  moe_mm<2><<<dim3(72, DIM / 128), 256, 0, stream>>>(
      hbuf, wT, b2, oe, DIM, FDIM, offsets, perm, tmap, tilecnt);

  combine_kernel<<<(T_TOK * DIM / 4) / 256, 256, 0, stream>>>(oe, ppos, topg, out);
}

// Round 13
// 976.223 us; speedup vs baseline: 1.0598x; 1.0598x over previous
//
#include <hip/hip_runtime.h>
#include <hip/hip_bf16.h>
#include <cstdint>
#include <cmath>

#define T_TOK 4096
#define DIM   768
#define HEADS 12
#define HD    64
#define NEXP  8
#define FDIM  3072

typedef __attribute__((ext_vector_type(8))) short short8v;
typedef __attribute__((ext_vector_type(4))) float float4v;

__device__ __forceinline__ float gelu_tanh(float x) {
  // matches jax.nn.gelu(approximate=True)
  float u = 0.7978845608028654f * (x + 0.044715f * x * x * x);
  return 0.5f * x * (1.0f + tanhf(u));
}

__device__ __forceinline__ short f2bf(float x) {
  __hip_bfloat16 h = __float2bfloat16(x);
  return *reinterpret_cast<short*>(&h);
}

// async global->LDS 16B copy: dest = (wave-uniform lds base) + lane*16,
// src is per-lane. LDS generic ptr low 32 bits == LDS byte offset on gfx9+.
__device__ __forceinline__ void gld16(void* lds, const void* g) {
  __builtin_amdgcn_global_load_lds(
      (__attribute__((address_space(1))) void*)(uintptr_t)g,
      (__attribute__((address_space(3))) void*)(uint32_t)(uintptr_t)lds,
      16, 0, 0);
}

// ---------------- fp32 tiled GEMM (attention path only: QKV, o-proj) --------
// float4-vectorized staging, 16x16 thread grid, BK=16.
// BFOUT: additionally write bf16 copy of C (fused y2bf for the o-proj).
template<int TBM, int TBN, bool BFOUT>
__global__ __launch_bounds__(256) void gemm_f32(
    const float* __restrict__ A, const float* __restrict__ W,
    const float* __restrict__ bias, float* __restrict__ C,
    short* __restrict__ Cbf, int M, int N, int K)
{
  constexpr int MM = TBM / 16;
  constexpr int MN = TBN / 16;
  constexpr int AL4 = TBM / 64;   // float4 A loads per thread
  constexpr int BL4 = TBN / 64;
  __shared__ float As[16][TBM + 4];
  __shared__ float Bs[16][TBN + 4];
  const int bm = blockIdx.y * TBM;
  const int bn = blockIdx.x * TBN;
  const int tid = threadIdx.x;
  const int tr = tid >> 4;
  const int tc = tid & 15;

  float acc[MM][MN] = {};

  for (int k0 = 0; k0 < K; k0 += 16) {
    #pragma unroll
    for (int i = 0; i < AL4; i++) {
      int fidx = tid + i * 256;
      int row = fidx >> 2, c4 = fidx & 3;
      float4 v = *(const float4*)&A[(size_t)(bm + row) * K + k0 + c4 * 4];
      As[c4 * 4 + 0][row] = v.x;
      As[c4 * 4 + 1][row] = v.y;
      As[c4 * 4 + 2][row] = v.z;
      As[c4 * 4 + 3][row] = v.w;
    }
    #pragma unroll
    for (int i = 0; i < BL4; i++) {
      int fidx = tid + i * 256;
      int kk = fidx / (TBN / 4), n4 = fidx % (TBN / 4);
      *(float4*)&Bs[kk][n4 * 4] =
          *(const float4*)&W[(size_t)(k0 + kk) * N + bn + n4 * 4];
    }
    __syncthreads();
    #pragma unroll
    for (int kk = 0; kk < 16; kk++) {
      float a[MM], b[MN];
      #pragma unroll
      for (int u4 = 0; u4 < MM / 4; u4++) {
        float4 t = *(const float4*)&As[kk][tr * MM + u4 * 4];
        a[u4*4+0]=t.x; a[u4*4+1]=t.y; a[u4*4+2]=t.z; a[u4*4+3]=t.w;
      }
      #pragma unroll
      for (int v4 = 0; v4 < MN / 4; v4++) {
        float4 t = *(const float4*)&Bs[kk][tc * MN + v4 * 4];
        b[v4*4+0]=t.x; b[v4*4+1]=t.y; b[v4*4+2]=t.z; b[v4*4+3]=t.w;
      }
      #pragma unroll
      for (int u = 0; u < MM; u++)
        #pragma unroll
        for (int v = 0; v < MN; v++)
          acc[u][v] = fmaf(a[u], b[v], acc[u][v]);
    }
    __syncthreads();
  }

  #pragma unroll
  for (int u = 0; u < MM; u++) {
    int row = bm + tr * MM + u;
    #pragma unroll
    for (int v4 = 0; v4 < MN / 4; v4++) {
      int col = bn + tc * MN + v4 * 4;
      float4 o;
      o.x = acc[u][v4*4+0] + bias[col+0];
      o.y = acc[u][v4*4+1] + bias[col+1];
      o.z = acc[u][v4*4+2] + bias[col+2];
      o.w = acc[u][v4*4+3] + bias[col+3];
      *(float4*)&C[(size_t)row * N + col] = o;
      if (BFOUT) {
        short4 s = make_short4(f2bf(o.x), f2bf(o.y), f2bf(o.z), f2bf(o.w));
        *(short4*)&Cbf[(size_t)row * N + col] = s;
      }
    }
  }
}

// ---------------- transpose + fp32->bf16 convert: W[K][N] -> WT[N][K] -------
__global__ __launch_bounds__(256) void transpose_bf16(
    const float* __restrict__ W, short* __restrict__ WT, int K, int N)
{
  __shared__ float t[32][33];
  const size_t mat = (size_t)K * N;
  const float* Wp = W + blockIdx.z * mat;
  short* WTp = WT + blockIdx.z * mat;
  int n0 = blockIdx.x * 32, k0 = blockIdx.y * 32;
  int tx = threadIdx.x, ty = threadIdx.y;  // 32 x 8
  #pragma unroll
  for (int i = 0; i < 4; i++)
    t[ty + i * 8][tx] = Wp[(size_t)(k0 + ty + i * 8) * N + n0 + tx];
  __syncthreads();
  #pragma unroll
  for (int i = 0; i < 4; i++)
    WTp[(size_t)(n0 + ty + i * 8) * K + k0 + tx] = f2bf(t[tx][ty + i * 8]);
}

// ---------------- unified MoE GEMM: 128x128 tile, BK=64, gld16 staging -----
// MODE 1 (up):   hbuf[start+r] = gelu(bf16(gather(ybf)@WT^T + b1))
// MODE 2 (down): oe[start+r]   = hbuf[start+r]@WT^T + b2   (fp32)
// Grid: (row-tile FASTEST for B-panel L2 reuse, N-panel on y).
// BK=64: 32 MFMA per barrier pair (halved barrier count vs BK=32).
template<int MODE>
__global__ __launch_bounds__(256) void moe_mm(
    const short* __restrict__ A, const short* __restrict__ WT,
    const float* __restrict__ bias, void* __restrict__ Cout,
    int N, int K,
    const int* __restrict__ offsets, const int* __restrict__ perm,
    const int* __restrict__ tmap, const int* __restrict__ tilecnt)
{
  const int bx = blockIdx.x;
  if (bx >= tilecnt[0]) return;
  const int info  = tmap[bx];
  const int e     = info >> 16;
  const int start = offsets[e];
  const int M     = offsets[e + 1] - start;
  const int bm    = (info & 0xffff) * 128;
  const int bn    = blockIdx.y * 128;

  __shared__ short As[8][128][8];   // [kslot][row][16B], 2 half-slabs of 4
  __shared__ short Bs[8][128][8];
  __shared__ int   perm_s[128];

  const int tid  = threadIdx.x;
  const int lane = tid & 63;
  const int wave = tid >> 6;        // staging kslots {wave, wave+4}; quadrant
  const int wm = wave >> 1, wn = wave & 1;
  const int lr = lane & 15;
  const int kb = lane >> 4;

  const short* WTe = WT + (size_t)e * ((size_t)N * K);
  const float* be  = bias + (size_t)e * N;

  if (MODE == 1) {
    if (tid < 128) {
      int rr = bm + tid;
      perm_s[tid] = (rr < M) ? perm[start + rr] : perm[start];
    }
    __syncthreads();
  }

  const short* asrc0;
  const short* asrc1;
  if (MODE == 1) {
    asrc0 = A + (size_t)perm_s[lane] * K + wave * 8;
    asrc1 = A + (size_t)perm_s[64 + lane] * K + wave * 8;
  } else {
    int r0 = bm + lane;      if (r0 >= M) r0 = M - 1;
    int r1 = bm + 64 + lane; if (r1 >= M) r1 = M - 1;
    asrc0 = A + (size_t)(start + r0) * K + wave * 8;
    asrc1 = A + (size_t)(start + r1) * K + wave * 8;
  }
  const short* bsrc0 = WTe + (size_t)(bn + lane) * K + wave * 8;
  const short* bsrc1 = WTe + (size_t)(bn + 64 + lane) * K + wave * 8;

  float4v acc[4][4] = {};

  for (int k0 = 0; k0 < K; k0 += 64) {
    __syncthreads();                 // previous slab's LDS reads done
    // first 32-k half into kslots [wave]
    gld16(&As[wave][0][0],  asrc0 + k0);
    gld16(&As[wave][64][0], asrc1 + k0);
    gld16(&Bs[wave][0][0],  bsrc0 + k0);
    gld16(&Bs[wave][64][0], bsrc1 + k0);
    // second 32-k half into kslots [wave+4]
    gld16(&As[wave + 4][0][0],  asrc0 + k0 + 32);
    gld16(&As[wave + 4][64][0], asrc1 + k0 + 32);
    gld16(&Bs[wave + 4][0][0],  bsrc0 + k0 + 32);
    gld16(&Bs[wave + 4][64][0], bsrc1 + k0 + 32);
    __syncthreads();                 // drains vmcnt -> slab visible

    #pragma unroll
    for (int hh = 0; hh < 2; hh++) {
      short8v af[4], bfv[4];
      #pragma unroll
      for (int mi = 0; mi < 4; mi++)
        af[mi] = *(const short8v*)&As[hh * 4 + kb][wm * 64 + mi * 16 + lr][0];
      #pragma unroll
      for (int ni = 0; ni < 4; ni++)
        bfv[ni] = *(const short8v*)&Bs[hh * 4 + kb][wn * 64 + ni * 16 + lr][0];
      #pragma unroll
      for (int mi = 0; mi < 4; mi++)
        #pragma unroll
        for (int ni = 0; ni < 4; ni++)
          acc[mi][ni] = __builtin_amdgcn_mfma_f32_16x16x32_bf16(
              af[mi], bfv[ni], acc[mi][ni], 0, 0, 0);
    }
  }

  // D mapping: col = lane&15, row = (lane>>4)*4 + reg
  #pragma unroll
  for (int ni = 0; ni < 4; ni++) {
    int col = bn + wn * 64 + ni * 16 + lr;
    float b = be[col];
    #pragma unroll
    for (int mi = 0; mi < 4; mi++) {
      int lrow0 = wm * 64 + mi * 16 + kb * 4;
      #pragma unroll
      for (int r = 0; r < 4; r++) {
        int rr = bm + lrow0 + r;
        if (rr < M) {
          if (MODE == 1) {
            short* C = (short*)Cout;
            C[(size_t)(start + rr) * N + col] = f2bf(gelu_tanh(acc[mi][ni][r] + b));
          } else {
            float* C = (float*)Cout;
            C[(size_t)(start + rr) * N + col] = acc[mi][ni][r] + b;
          }
        }
      }
    }
  }
}

// ---------------- combine: out[t] = g0*oe[p0] + g1*oe[p1] -------------------
__global__ __launch_bounds__(256) void combine_kernel(
    const float* __restrict__ oe, const int* __restrict__ ppos,
    const float* __restrict__ topg, float* __restrict__ out)
{
  int g = blockIdx.x * 256 + threadIdx.x;
  int t = g / 192;
  int c = (g - t * 192) * 4;
  int p0 = ppos[2 * t], p1 = ppos[2 * t + 1];
  float g0 = topg[2 * t], g1 = topg[2 * t + 1];
  float4 a = *(const float4*)&oe[(size_t)p0 * DIM + c];
  float4 b = *(const float4*)&oe[(size_t)p1 * DIM + c];
  float4 o;
  o.x = g0 * a.x + g1 * b.x;
  o.y = g0 * a.y + g1 * b.y;
  o.z = g0 * a.z + g1 * b.z;
  o.w = g0 * a.w + g1 * b.w;
  *(float4*)&out[(size_t)t * DIM + c] = o;
}

// ---------------- attention (fp32, no-max softmax, 8 waves) ----------------
// EXACT r8 structure (best measured: 296us across r7-r12 variants).
// grid (16,48), block 512 = 8 waves: wave = (kq 0..3, qhalf 0..1).
// Lane: grp owns 2 queries, sub owns 16 dims. Keys split 4-way across kq;
// 4-stage pairwise combine in ks/vs scratch.
__global__ __launch_bounds__(512) void attn_kernel(
    const float* __restrict__ qkv, float* __restrict__ ctx)
{
  const int qt = blockIdx.x;
  const int bh = blockIdx.y;
  const int b = bh / HEADS, h = bh % HEADS;
  const float* base = qkv + (size_t)b * 1024 * (3 * DIM) + h * 64;

  __shared__ float ks[64 * 64];           // K tile; combine scratch
  __shared__ float vs[64 * 64];           // V tile; combine scratch
  __shared__ float lred[2][2][32];

  const int tid   = threadIdx.x;
  const int wv    = tid >> 6;
  const int qhalf = wv & 1;
  const int kq    = wv >> 1;          // 0..3
  const int lane  = tid & 63;
  const int grp   = lane >> 2;        // 0..15
  const int sub   = lane & 3;         // 0..3
  const int q0    = qhalf * 32 + grp * 2;
  const int dpart = sub * 16;

  const float qscale = 0.125f * 1.44269504088896f;  // fold 1/sqrt(64), log2e
  float qA[16], qB[16], accA[16] = {}, accB[16] = {};
  float lA = 0.f, lB = 0.f;

  {
    const float* qpA = base + (size_t)(qt * 64 + q0) * (3 * DIM) + dpart;
    const float* qpB = qpA + 3 * DIM;
    #pragma unroll
    for (int d4 = 0; d4 < 4; d4++) {
      float4 ta = *(const float4*)(qpA + d4 * 4);
      float4 tb = *(const float4*)(qpB + d4 * 4);
      qA[d4*4+0]=ta.x*qscale; qA[d4*4+1]=ta.y*qscale; qA[d4*4+2]=ta.z*qscale; qA[d4*4+3]=ta.w*qscale;
      qB[d4*4+0]=tb.x*qscale; qB[d4*4+1]=tb.y*qscale; qB[d4*4+2]=tb.z*qscale; qB[d4*4+3]=tb.w*qscale;
    }
  }

  for (int kt = 0; kt < 16; kt++) {
    __syncthreads();
    #pragma unroll
    for (int i = 0; i < 2; i++) {
      int idx = tid + i * 512;          // 0..1023
      int r = idx >> 4, c4 = idx & 15;
      const float* kp = base + (size_t)(kt * 64 + r) * (3 * DIM) + c4 * 4;
      *(float4*)&ks[r * 64 + c4 * 4] = *(const float4*)(kp + DIM);
      *(float4*)&vs[r * 64 + c4 * 4] = *(const float4*)(kp + 2 * DIM);
    }
    __syncthreads();

    #pragma unroll 2
    for (int jj = 0; jj < 16; jj++) {
      int j = kq * 16 + jj;
      float4 k0v = *(const float4*)&ks[j * 64 + dpart];
      float4 k1v = *(const float4*)&ks[j * 64 + dpart + 4];
      float4 k2v = *(const float4*)&ks[j * 64 + dpart + 8];
      float4 k3v = *(const float4*)&ks[j * 64 + dpart + 12];
      float kr[16] = {k0v.x,k0v.y,k0v.z,k0v.w, k1v.x,k1v.y,k1v.z,k1v.w,
                      k2v.x,k2v.y,k2v.z,k2v.w, k3v.x,k3v.y,k3v.z,k3v.w};
      float sA = 0.f, sB = 0.f;
      #pragma unroll
      for (int d = 0; d < 16; d++) {
        sA = fmaf(qA[d], kr[d], sA);
        sB = fmaf(qB[d], kr[d], sB);
      }
      sA += __shfl_xor(sA, 1);  sB += __shfl_xor(sB, 1);
      sA += __shfl_xor(sA, 2);  sB += __shfl_xor(sB, 2);
      float pA = exp2f(sA);
      float pB = exp2f(sB);
      lA += pA;  lB += pB;
      float4 v0v = *(const float4*)&vs[j * 64 + dpart];
      float4 v1v = *(const float4*)&vs[j * 64 + dpart + 4];
      float4 v2v = *(const float4*)&vs[j * 64 + dpart + 8];
      float4 v3v = *(const float4*)&vs[j * 64 + dpart + 12];
      float vr[16] = {v0v.x,v0v.y,v0v.z,v0v.w, v1v.x,v1v.y,v1v.z,v1v.w,
                      v2v.x,v2v.y,v2v.z,v2v.w, v3v.x,v3v.y,v3v.z,v3v.w};
      #pragma unroll
      for (int d = 0; d < 16; d++) {
        accA[d] = fmaf(pA, vr[d], accA[d]);
        accB[d] = fmaf(pB, vr[d], accB[d]);
      }
    }
  }

  // 4-stage pairwise combine using ks/vs as scratch:
  //   A: kq2 -> ks[qh], kq3 -> vs[qh]
  //   B: kq0 += ks[qh], kq1 += vs[qh]
  //   C: kq1 -> ks[qh]
  //   D: kq0 += ks[qh]; normalize; store
  float* regA = ks + qhalf * 2048;   // 32 q-rows x 64 dims
  float* regB = vs + qhalf * 2048;
  const int r0 = (grp * 2) * 64 + dpart;
  const int r1 = r0 + 64;

  __syncthreads();
  if (kq == 2 || kq == 3) {
    float* buf = (kq == 2) ? regA : regB;
    #pragma unroll
    for (int d4 = 0; d4 < 4; d4++) {
      *(float4*)&buf[r0 + d4*4] =
          make_float4(accA[d4*4], accA[d4*4+1], accA[d4*4+2], accA[d4*4+3]);
      *(float4*)&buf[r1 + d4*4] =
          make_float4(accB[d4*4], accB[d4*4+1], accB[d4*4+2], accB[d4*4+3]);
    }
    if (sub == 0) {
      lred[kq - 2][qhalf][grp * 2]     = lA;
      lred[kq - 2][qhalf][grp * 2 + 1] = lB;
    }
  }
  __syncthreads();
  if (kq == 0 || kq == 1) {
    const float* buf = (kq == 0) ? regA : regB;
    #pragma unroll
    for (int d4 = 0; d4 < 4; d4++) {
      float4 a = *(const float4*)&buf[r0 + d4*4];
      float4 c = *(const float4*)&buf[r1 + d4*4];
      accA[d4*4+0] += a.x; accA[d4*4+1] += a.y; accA[d4*4+2] += a.z; accA[d4*4+3] += a.w;
      accB[d4*4+0] += c.x; accB[d4*4+1] += c.y; accB[d4*4+2] += c.z; accB[d4*4+3] += c.w;
    }
    lA += lred[kq][qhalf][grp * 2];
    lB += lred[kq][qhalf][grp * 2 + 1];
  }
  __syncthreads();
  if (kq == 1) {
    #pragma unroll
    for (int d4 = 0; d4 < 4; d4++) {
      *(float4*)&regA[r0 + d4*4] =
          make_float4(accA[d4*4], accA[d4*4+1], accA[d4*4+2], accA[d4*4+3]);
      *(float4*)&regA[r1 + d4*4] =
          make_float4(accB[d4*4], accB[d4*4+1], accB[d4*4+2], accB[d4*4+3]);
    }
    if (sub == 0) {
      lred[0][qhalf][grp * 2]     = lA;
      lred[0][qhalf][grp * 2 + 1] = lB;
    }
  }
  __syncthreads();
  if (kq == 0) {
    #pragma unroll
    for (int d4 = 0; d4 < 4; d4++) {
      float4 a = *(const float4*)&regA[r0 + d4*4];
      float4 c = *(const float4*)&regA[r1 + d4*4];
      accA[d4*4+0] += a.x; accA[d4*4+1] += a.y; accA[d4*4+2] += a.z; accA[d4*4+3] += a.w;
      accB[d4*4+0] += c.x; accB[d4*4+1] += c.y; accB[d4*4+2] += c.z; accB[d4*4+3] += c.w;
    }
    lA += lred[0][qhalf][grp * 2];
    lB += lred[0][qhalf][grp * 2 + 1];
    float invA = 1.f / lA, invB = 1.f / lB;
    float* opA = ctx + ((size_t)b * 1024 + qt * 64 + q0) * DIM + h * 64 + dpart;
    float* opB = opA + DIM;
    #pragma unroll
    for (int d4 = 0; d4 < 4; d4++) {
      float4 oa, ob;
      oa.x = accA[d4*4+0]*invA; oa.y = accA[d4*4+1]*invA;
      oa.z = accA[d4*4+2]*invA; oa.w = accA[d4*4+3]*invA;
      ob.x = accB[d4*4+0]*invB; ob.y = accB[d4*4+1]*invB;
      ob.z = accB[d4*4+2]*invB; ob.w = accB[d4*4+3]*invB;
      *(float4*)(opA + d4 * 4) = oa;
      *(float4*)(opB + d4 * 4) = ob;
    }
  }
}

// ---------------- router ----------------
__global__ __launch_bounds__(256) void router_kernel(
    const float* __restrict__ y, const float* __restrict__ wr,
    float* __restrict__ probs, int* __restrict__ topi,
    float* __restrict__ topg, int* __restrict__ counts)
{
  __shared__ float w[DIM * NEXP];
  const int tid = threadIdx.x;
  for (int i = tid; i < DIM * NEXP; i += 256) w[i] = wr[i];
  __syncthreads();

  const int t = blockIdx.x * 256 + tid;
  const float* yp = y + (size_t)t * DIM;
  float logit[8] = {};
  for (int d = 0; d < DIM; d++) {
    float xv = yp[d];
    #pragma unroll
    for (int e = 0; e < 8; e++) logit[e] = fmaf(xv, w[d * 8 + e], logit[e]);
  }
  float mx = logit[0];
  #pragma unroll
  for (int e = 1; e < 8; e++) mx = fmaxf(mx, logit[e]);
  float p[8], sum = 0.f;
  #pragma unroll
  for (int e = 0; e < 8; e++) { p[e] = __expf(logit[e] - mx); sum += p[e]; }
  float inv = 1.f / sum;
  #pragma unroll
  for (int e = 0; e < 8; e++) { p[e] *= inv; probs[(size_t)t * 8 + e] = p[e]; }

  int i0 = 0;
  #pragma unroll
  for (int e = 1; e < 8; e++) if (p[e] > p[i0]) i0 = e;
  int i1 = (i0 == 0) ? 1 : 0;
  #pragma unroll
  for (int e = 0; e < 8; e++) if (e != i0 && p[e] > p[i1]) i1 = e;
  float g = p[i0] + p[i1];
  topi[2 * t] = i0;  topi[2 * t + 1] = i1;
  topg[2 * t] = p[i0] / g;  topg[2 * t + 1] = p[i1] / g;
  atomicAdd(&counts[i0], 1);
  atomicAdd(&counts[i1], 1);
}

__global__ void init_meta(int* counts) {
  if (threadIdx.x < 8) counts[threadIdx.x] = 0;
}

// scan + compact 128-row tile map (shared by up and down)
__global__ void scan_kernel(const int* __restrict__ counts,
                            int* __restrict__ offsets, int* __restrict__ cursors,
                            int* __restrict__ tmap, int* __restrict__ tilecnt) {
  if (threadIdx.x == 0) {
    int s = 0;
    for (int e = 0; e < 8; e++) { offsets[e] = s; cursors[e] = s; s += counts[e]; }
    offsets[8] = s;
    int tu = 0;
    for (int e = 0; e < 8; e++) {
      int m = counts[e];
      for (int t = 0; t * 128 < m; t++) tmap[tu++] = (e << 16) | t;
    }
    tilecnt[0] = tu;
  }
}

__global__ __launch_bounds__(256) void scatter_kernel(
    const int* __restrict__ topi, int* __restrict__ cursors,
    int* __restrict__ perm, int* __restrict__ ppos)
{
  const int t = blockIdx.x * 256 + threadIdx.x;
  #pragma unroll
  for (int s = 0; s < 2; s++) {
    int e = topi[2 * t + s];
    int pos = atomicAdd(&cursors[e], 1);
    perm[pos] = t;
    ppos[2 * t + s] = pos;
  }
}

// ---------------- launch ----------------
extern "C" void kernel_launch(void* const* d_in, const int* in_sizes, int n_in,
                              void* d_out, int out_size, void* d_ws, size_t ws_size,
                              hipStream_t stream) {
  const float* x        = (const float*)d_in[0];
  const float* w_qkv    = (const float*)d_in[1];
  const float* b_qkv    = (const float*)d_in[2];
  const float* w_o      = (const float*)d_in[3];
  const float* b_o      = (const float*)d_in[4];
  const float* w_router = (const float*)d_in[5];
  const float* w1       = (const float*)d_in[6];
  const float* b1       = (const float*)d_in[7];
  const float* w2       = (const float*)d_in[8];
  const float* b2       = (const float*)d_in[9];

  float* out   = (float*)d_out;
  float* probs = out + (size_t)T_TOK * DIM;

  char* ws = (char*)d_ws;
  // region A [0, 50331648): qkv f32 (37.75MB) -> hbuf bf16 (50.33MB)
  float* qkv  = (float*)ws;
  short* hbuf = (short*)ws;
  // wT [50331648, 88080384)
  short* wT   = (short*)(ws + 50331648);
  // region C [88080384, 113246208): ctx f32 | later oe f32
  float* ctx  = (float*)(ws + 88080384);
  float* oe   = (float*)(ws + 88080384);
  float* y    = (float*)(ws + 100663296);    // 12.58MB: y f32 [4096*768]
  short* ybf  = (short*)(ws + 113246208);    // 6.29MB: y bf16
  char*  meta = ws + 119537664;
  int*   counts  = (int*)meta;
  int*   cursors = counts + 8;
  int*   offsets = cursors + 8;              // 16 slots
  int*   topi    = offsets + 16;             // 8192
  float* topg    = (float*)(topi + 8192);
  int*   perm    = (int*)(topg + 8192);
  int*   ppos    = perm + 8192;
  int*   tmap    = ppos + 8192;              // <= 72
  int*   tilecnt = tmap + 80;

  init_meta<<<1, 64, 0, stream>>>(counts);

  // QKV (fp32): [4096,768] @ [768,2304], 128x128 tile
  gemm_f32<128, 128, false><<<dim3((3 * DIM) / 128, T_TOK / 128), 256, 0, stream>>>(
      x, w_qkv, b_qkv, qkv, nullptr, T_TOK, 3 * DIM, DIM);

  attn_kernel<<<dim3(16, 48), 512, 0, stream>>>(qkv, ctx);

  // output proj (fp32): [4096,768] @ [768,768]; fused bf16 copy for MoE
  gemm_f32<64, 64, true><<<dim3(DIM / 64, T_TOK / 64), 256, 0, stream>>>(
      ctx, w_o, b_o, y, ybf, T_TOK, DIM, DIM);

  router_kernel<<<16, 256, 0, stream>>>(y, w_router, probs, topi, topg, counts);
  scan_kernel<<<1, 64, 0, stream>>>(counts, offsets, cursors, tmap, tilecnt);
  scatter_kernel<<<16, 256, 0, stream>>>(topi, cursors, perm, ppos);

  // w1 [8][768][3072] -> w1t bf16 [8][3072][768]
  transpose_bf16<<<dim3(FDIM / 32, DIM / 32, NEXP), dim3(32, 8), 0, stream>>>(
      w1, wT, DIM, FDIM);
  // up: row-tiles fastest (L2 B-panel reuse), <=72 active tiles
  moe_mm<1><<<dim3(72, FDIM / 128), 256, 0, stream>>>(
      ybf, wT, b1, hbuf, FDIM, DIM, offsets, perm, tmap, tilecnt);

  // w2 [8][3072][768] -> w2t bf16 [8][768][3072]
  transpose_bf16<<<dim3(DIM / 32, FDIM / 32, NEXP), dim3(32, 8), 0, stream>>>(
      w2, wT, FDIM, DIM);
  // down: same 128-row tile map
  moe_mm<2><<<dim3(72, DIM / 128), 256, 0, stream>>>(
      hbuf, wT, b2, oe, DIM, FDIM, offsets, perm, tmap, tilecnt);

  combine_kernel<<<(T_TOK * DIM / 4) / 256, 256, 0, stream>>>(oe, ppos, topg, out);
}